// Round 1
// baseline (799.666 us; speedup 1.0000x reference)
//
#include <hip/hip_runtime.h>

// GAE forward on MI355X.
// Pipeline: cast -> t1T=W1T@featT -> h1=relu(adj@t1+b1) [split-K] ->
//           t2T=W2T@h1T -> h=adj@t2+b2 [split-K] -> out=sigmoid(h@hT), h.
// All MFMA GEMMs use the "bt" convention: X[M,K], Y[N,K] row-major, C = X*Y^T.
// Frag layout (m89-verified): A/B lane = X[l16][k+q*8..+8] (16B load);
// C/D: col = lane&15, row = q*4 + reg.

typedef __bf16 bf16x8_t __attribute__((ext_vector_type(8)));
typedef __bf16 bf16x4_t __attribute__((ext_vector_type(4)));
typedef float  f32x4_t  __attribute__((ext_vector_type(4)));

#define MFMA_BF16(a, b, c) __builtin_amdgcn_mfma_f32_16x16x32_bf16((a), (b), (c), 0, 0, 0)

__device__ __forceinline__ bf16x8_t cvt8(float4 u, float4 v) {
    bf16x8_t o;
    o[0] = (__bf16)u.x; o[1] = (__bf16)u.y; o[2] = (__bf16)u.z; o[3] = (__bf16)u.w;
    o[4] = (__bf16)v.x; o[5] = (__bf16)v.y; o[6] = (__bf16)v.z; o[7] = (__bf16)v.w;
    return o;
}

// ---- cast feature -> bf16 (8 elems/thread), W1 -> W1T bf16, W2 -> W2T bf16 ----
__global__ __launch_bounds__(256) void cast_all(
    const float* __restrict__ feat, const float* __restrict__ W1,
    const float* __restrict__ W2, __bf16* __restrict__ fb,
    __bf16* __restrict__ w1t, __bf16* __restrict__ w2t)
{
    const int j = blockIdx.x * 256 + threadIdx.x;
    if (j < 524288) {                     // feature: 8192*512 / 8
        const float4* p = (const float4*)feat + (size_t)j * 2;
        float4 u = p[0], v = p[1];
        *(bf16x8_t*)(fb + (size_t)j * 8) = cvt8(u, v);
    } else if (j < 524288 + 131072) {     // W1 [512][256] -> W1T [256][512]
        int t = j - 524288;
        int k = t >> 8, n = t & 255;
        w1t[n * 512 + k] = (__bf16)W1[t];
    } else if (j < 524288 + 131072 + 32768) { // W2 [256][128] -> W2T [128][256]
        int t = j - 655360;
        int k = t >> 7, n = t & 127;
        w2t[n * 256 + k] = (__bf16)W2[t];
    }
}

// ---- small bf16 GEMM, C (bf16) = X * Y^T.  4 waves as (4/WC) x WC grid,
// wave tile = MT m-tiles x 4 n-tiles of 16x16. BM = (4/WC)*MT*16, BN = WC*64. ----
template<int MT, int WC>
__global__ __launch_bounds__(256, 2) void gemm_bt_cbf16(
    const __bf16* __restrict__ X, const __bf16* __restrict__ Yb,
    __bf16* __restrict__ C, int K, int N)
{
    constexpr int WR = 4 / WC;
    constexpr int BM = WR * MT * 16;
    constexpr int BN = WC * 64;
    const int mblk = blockIdx.x, nblk = blockIdx.y;
    const int w = threadIdx.x >> 6, lane = threadIdx.x & 63;
    const int wr = w / WC, wc = w % WC;
    const int q = lane >> 4, l16 = lane & 15;
    const int mbase = mblk * BM + wr * (MT * 16);
    const int nbase = nblk * BN + wc * 64;

    f32x4_t acc[MT][4];
    const f32x4_t z = {0.f, 0.f, 0.f, 0.f};
#pragma unroll
    for (int i = 0; i < MT; i++)
#pragma unroll
        for (int jj = 0; jj < 4; jj++) acc[i][jj] = z;

    const __bf16* Xr[MT];
    const __bf16* Yr[4];
#pragma unroll
    for (int i = 0; i < MT; i++) Xr[i] = X + (size_t)(mbase + i * 16 + l16) * K + q * 8;
#pragma unroll
    for (int jj = 0; jj < 4; jj++) Yr[jj] = Yb + (size_t)(nbase + jj * 16 + l16) * K + q * 8;

    for (int k = 0; k < K; k += 32) {
        bf16x8_t a[MT], b[4];
#pragma unroll
        for (int i = 0; i < MT; i++) a[i] = *(const bf16x8_t*)(Xr[i] + k);
#pragma unroll
        for (int jj = 0; jj < 4; jj++) b[jj] = *(const bf16x8_t*)(Yr[jj] + k);
#pragma unroll
        for (int i = 0; i < MT; i++)
#pragma unroll
            for (int jj = 0; jj < 4; jj++) acc[i][jj] = MFMA_BF16(a[i], b[jj], acc[i][jj]);
    }

#pragma unroll
    for (int i = 0; i < MT; i++)
#pragma unroll
        for (int jj = 0; jj < 4; jj++) {
            const int row0 = mbase + i * 16 + q * 4;
            const int col = nbase + jj * 16 + l16;
#pragma unroll
            for (int r = 0; r < 4; r++)
                C[(size_t)(row0 + r) * N + col] = (__bf16)acc[i][jj][r];
        }
}

// ---- adj GEMM with inline fp32->bf16 on A, split-K partials.
// A fp32 [8192][8192]; Y bf16 [NN][8192]; P fp32 [KS=4][8192][NN].
// BM=64 rows per block, BN=NN full width (adj read exactly once per GEMM). ----
template<int MT, int WC>
__global__ __launch_bounds__(256, 2) void gemm_adj_splitk(
    const float* __restrict__ A, const __bf16* __restrict__ Y,
    float* __restrict__ P, int kchunk)
{
    constexpr int NN = WC * 64;
    const int mblk = blockIdx.x;
    const int ks = blockIdx.y;
    const int w = threadIdx.x >> 6, lane = threadIdx.x & 63;
    const int wr = w / WC, wc = w % WC;
    const int q = lane >> 4, l16 = lane & 15;
    const int mbase = mblk * 64 + wr * (MT * 16);
    const int nbase = wc * 64;
    const int kbase = ks * kchunk;
    const int kend = kbase + kchunk;

    f32x4_t acc[MT][4];
    const f32x4_t z = {0.f, 0.f, 0.f, 0.f};
#pragma unroll
    for (int i = 0; i < MT; i++)
#pragma unroll
        for (int jj = 0; jj < 4; jj++) acc[i][jj] = z;

    const float* Ar[MT];
    const __bf16* Yr[4];
#pragma unroll
    for (int i = 0; i < MT; i++) Ar[i] = A + (size_t)(mbase + i * 16 + l16) * 8192 + q * 8;
#pragma unroll
    for (int jj = 0; jj < 4; jj++) Yr[jj] = Y + (size_t)(nbase + jj * 16 + l16) * 8192 + q * 8;

    bf16x8_t a[MT], b[4];
#pragma unroll
    for (int i = 0; i < MT; i++) {
        float4 u = *(const float4*)(Ar[i] + kbase);
        float4 v = *(const float4*)(Ar[i] + kbase + 4);
        a[i] = cvt8(u, v);
    }
#pragma unroll
    for (int jj = 0; jj < 4; jj++) b[jj] = *(const bf16x8_t*)(Yr[jj] + kbase);

    for (int k = kbase + 32; k < kend; k += 32) {
        float4 u[MT], v[MT];
        bf16x8_t nb[4];
#pragma unroll
        for (int i = 0; i < MT; i++) {
            u[i] = *(const float4*)(Ar[i] + k);
            v[i] = *(const float4*)(Ar[i] + k + 4);
        }
#pragma unroll
        for (int jj = 0; jj < 4; jj++) nb[jj] = *(const bf16x8_t*)(Yr[jj] + k);
#pragma unroll
        for (int i = 0; i < MT; i++)
#pragma unroll
            for (int jj = 0; jj < 4; jj++) acc[i][jj] = MFMA_BF16(a[i], b[jj], acc[i][jj]);
#pragma unroll
        for (int i = 0; i < MT; i++) a[i] = cvt8(u[i], v[i]);
#pragma unroll
        for (int jj = 0; jj < 4; jj++) b[jj] = nb[jj];
    }
#pragma unroll
    for (int i = 0; i < MT; i++)
#pragma unroll
        for (int jj = 0; jj < 4; jj++) acc[i][jj] = MFMA_BF16(a[i], b[jj], acc[i][jj]);

#pragma unroll
    for (int i = 0; i < MT; i++)
#pragma unroll
        for (int jj = 0; jj < 4; jj++) {
            const int row0 = mbase + i * 16 + q * 4;
            const int col = nbase + jj * 16 + l16;
            float* pp = P + ((size_t)ks * 8192 + row0) * NN + col;
#pragma unroll
            for (int r = 0; r < 4; r++) pp[(size_t)r * NN] = acc[i][jj][r];
        }
}

// ---- epilogue 1: h1 = relu(sum_ks partial + b1) -> bf16 [8192][256] ----
__global__ __launch_bounds__(256) void epi_relu_bias(
    const float* __restrict__ P, const float* __restrict__ bias,
    __bf16* __restrict__ H)
{
    const size_t SL = (size_t)8192 * 256;
    const size_t idx = ((size_t)blockIdx.x * 256 + threadIdx.x) * 4;
    float4 s0 = *(const float4*)(P + idx);
    float4 s1 = *(const float4*)(P + SL + idx);
    float4 s2 = *(const float4*)(P + 2 * SL + idx);
    float4 s3 = *(const float4*)(P + 3 * SL + idx);
    const int col = (int)(idx & 255);
    float4 bb = *(const float4*)(bias + col);
    float r0 = fmaxf(s0.x + s1.x + s2.x + s3.x + bb.x, 0.f);
    float r1 = fmaxf(s0.y + s1.y + s2.y + s3.y + bb.y, 0.f);
    float r2 = fmaxf(s0.z + s1.z + s2.z + s3.z + bb.z, 0.f);
    float r3 = fmaxf(s0.w + s1.w + s2.w + s3.w + bb.w, 0.f);
    bf16x4_t o;
    o[0] = (__bf16)r0; o[1] = (__bf16)r1; o[2] = (__bf16)r2; o[3] = (__bf16)r3;
    *(bf16x4_t*)(H + idx) = o;
}

// ---- epilogue 2: h = sum_ks partial + b2 -> fp32 d_out tail AND bf16 copy ----
__global__ __launch_bounds__(256) void epi_bias_out(
    const float* __restrict__ P, const float* __restrict__ bias,
    float* __restrict__ Hout, __bf16* __restrict__ Hbf)
{
    const size_t SL = (size_t)8192 * 128;
    const size_t idx = ((size_t)blockIdx.x * 256 + threadIdx.x) * 4;
    float4 s0 = *(const float4*)(P + idx);
    float4 s1 = *(const float4*)(P + SL + idx);
    float4 s2 = *(const float4*)(P + 2 * SL + idx);
    float4 s3 = *(const float4*)(P + 3 * SL + idx);
    const int col = (int)(idx & 127);
    float4 bb = *(const float4*)(bias + col);
    float4 o;
    o.x = s0.x + s1.x + s2.x + s3.x + bb.x;
    o.y = s0.y + s1.y + s2.y + s3.y + bb.y;
    o.z = s0.z + s1.z + s2.z + s3.z + bb.z;
    o.w = s0.w + s1.w + s2.w + s3.w + bb.w;
    *(float4*)(Hout + idx) = o;
    bf16x4_t ob;
    ob[0] = (__bf16)o.x; ob[1] = (__bf16)o.y; ob[2] = (__bf16)o.z; ob[3] = (__bf16)o.w;
    *(bf16x4_t*)(Hbf + idx) = ob;
}

// ---- decoder: out[r][s] = sigmoid(h[r,:].h[s,:]), K=128 unrolled.
// 128x128 block tile, 4 waves (2x2), wave tile 64x64. Write-bound (256 MB). ----
__global__ __launch_bounds__(256, 2) void gemm_sig(
    const __bf16* __restrict__ H, float* __restrict__ out)
{
    const int mblk = blockIdx.x, nblk = blockIdx.y;
    const int w = threadIdx.x >> 6, lane = threadIdx.x & 63;
    const int wr = w >> 1, wc = w & 1;
    const int q = lane >> 4, l16 = lane & 15;
    const int mbase = mblk * 128 + wr * 64;
    const int nbase = nblk * 128 + wc * 64;

    f32x4_t acc[4][4];
    const f32x4_t z = {0.f, 0.f, 0.f, 0.f};
#pragma unroll
    for (int i = 0; i < 4; i++)
#pragma unroll
        for (int jj = 0; jj < 4; jj++) acc[i][jj] = z;

#pragma unroll
    for (int k = 0; k < 128; k += 32) {
        bf16x8_t a[4], b[4];
#pragma unroll
        for (int i = 0; i < 4; i++)
            a[i] = *(const bf16x8_t*)(H + (size_t)(mbase + i * 16 + l16) * 128 + k + q * 8);
#pragma unroll
        for (int jj = 0; jj < 4; jj++)
            b[jj] = *(const bf16x8_t*)(H + (size_t)(nbase + jj * 16 + l16) * 128 + k + q * 8);
#pragma unroll
        for (int i = 0; i < 4; i++)
#pragma unroll
            for (int jj = 0; jj < 4; jj++) acc[i][jj] = MFMA_BF16(a[i], b[jj], acc[i][jj]);
    }

#pragma unroll
    for (int i = 0; i < 4; i++)
#pragma unroll
        for (int jj = 0; jj < 4; jj++) {
            const int row0 = mbase + i * 16 + q * 4;
            const int col = nbase + jj * 16 + l16;
#pragma unroll
            for (int r = 0; r < 4; r++) {
                float x = acc[i][jj][r];
                out[(size_t)(row0 + r) * 8192 + col] = 1.0f / (1.0f + __expf(-x));
            }
        }
}

extern "C" void kernel_launch(void* const* d_in, const int* in_sizes, int n_in,
                              void* d_out, int out_size, void* d_ws, size_t ws_size,
                              hipStream_t stream)
{
    const float* adj  = (const float*)d_in[0];
    const float* feat = (const float*)d_in[1];
    const float* W1   = (const float*)d_in[2];
    const float* b1   = (const float*)d_in[3];
    const float* W2   = (const float*)d_in[4];
    const float* b2   = (const float*)d_in[5];
    float* out = (float*)d_out;

    // workspace layout (~52.3 MB total)
    char* p = (char*)d_ws;
    __bf16* featbf = (__bf16*)p; p += (size_t)8192 * 512 * 2;  // 8 MB
    __bf16* W1T    = (__bf16*)p; p += (size_t)256 * 512 * 2;   // 256 KB
    __bf16* W2T    = (__bf16*)p; p += (size_t)128 * 256 * 2;   // 64 KB
    __bf16* t1T    = (__bf16*)p; p += (size_t)256 * 8192 * 2;  // 4 MB
    __bf16* h1     = (__bf16*)p; p += (size_t)8192 * 256 * 2;  // 4 MB
    __bf16* t2T    = (__bf16*)p; p += (size_t)128 * 8192 * 2;  // 2 MB
    __bf16* hbf    = (__bf16*)p; p += (size_t)8192 * 128 * 2;  // 2 MB
    float* part    = (float*)p;                                 // 32 MB (reused 16 MB)

    // 1. casts
    cast_all<<<2688, 256, 0, stream>>>(feat, W1, W2, featbf, W1T, W2T);
    // 2. t1T[256][8192] = W1T * feat^T
    gemm_bt_cbf16<2, 2><<<dim3(4, 64), 256, 0, stream>>>(W1T, featbf, t1T, 512, 8192);
    // 3. partials of adj @ t1  (split-K=4)
    gemm_adj_splitk<4, 4><<<dim3(128, 4), 256, 0, stream>>>(adj, t1T, part, 2048);
    // 4. h1 = relu(sum + b1) -> bf16
    epi_relu_bias<<<2048, 256, 0, stream>>>(part, b1, h1);
    // 5. t2T[128][8192] = W2T * h1^T
    gemm_bt_cbf16<2, 2><<<dim3(2, 64), 256, 0, stream>>>(W2T, h1, t2T, 256, 8192);
    // 6. partials of adj @ t2  (split-K=4)
    gemm_adj_splitk<2, 2><<<dim3(128, 4), 256, 0, stream>>>(adj, t2T, part, 2048);
    // 7. h = sum + b2 -> fp32 out tail + bf16 copy
    epi_bias_out<<<1024, 256, 0, stream>>>(part, b2, out + (size_t)8192 * 8192, hbf);
    // 8. out = sigmoid(h @ h^T)
    gemm_sig<<<dim3(64, 64), 256, 0, stream>>>(hbf, out);
}

// Round 2
// 719.262 us; speedup vs baseline: 1.1118x; 1.1118x over previous
//
#include <hip/hip_runtime.h>

// GAE forward on MI355X.
// Pipeline: cast -> t1T=W1T@featT -> h1=relu(adj@t1+b1) [split-K] ->
//           t2T=W2T@h1T -> h=adj@t2+b2 [split-K] -> out=sigmoid(h@hT), h.
// All MFMA GEMMs use the "bt" convention: X[M,K], Y[N,K] row-major, C = X*Y^T.
// Frag layout (m89-verified): A/B lane = X[l16][k+q*8..+8] (16B load);
// C/D: col = lane&15, row = q*4 + reg.
//
// R2: adj-GEMMs rebuilt on the m97 structure — fp32 adj staged via
// global_load_lds dwordx4 into double-buffered LDS (BM=64 x BK=64 tiles),
// XOR-swizzled at 16B granularity (source-column swizzle; LDS dst must stay
// contiguous for the DMA). Reader XORs back per 16B half -> 2-way banks (free).

typedef __bf16 bf16x8_t __attribute__((ext_vector_type(8)));
typedef __bf16 bf16x4_t __attribute__((ext_vector_type(4)));
typedef float  f32x4_t  __attribute__((ext_vector_type(4)));

#define MFMA_BF16(a, b, c) __builtin_amdgcn_mfma_f32_16x16x32_bf16((a), (b), (c), 0, 0, 0)

__device__ __forceinline__ bf16x8_t cvt8(float4 u, float4 v) {
    bf16x8_t o;
    o[0] = (__bf16)u.x; o[1] = (__bf16)u.y; o[2] = (__bf16)u.z; o[3] = (__bf16)u.w;
    o[4] = (__bf16)v.x; o[5] = (__bf16)v.y; o[6] = (__bf16)v.z; o[7] = (__bf16)v.w;
    return o;
}

__device__ __forceinline__ void gload_lds16(const float* g, float* l) {
    __builtin_amdgcn_global_load_lds(
        (const __attribute__((address_space(1))) unsigned int*)g,
        (__attribute__((address_space(3))) unsigned int*)l, 16, 0, 0);
}

// ---- cast feature -> bf16 (8 elems/thread), W1 -> W1T bf16, W2 -> W2T bf16 ----
__global__ __launch_bounds__(256) void cast_all(
    const float* __restrict__ feat, const float* __restrict__ W1,
    const float* __restrict__ W2, __bf16* __restrict__ fb,
    __bf16* __restrict__ w1t, __bf16* __restrict__ w2t)
{
    const int j = blockIdx.x * 256 + threadIdx.x;
    if (j < 524288) {                     // feature: 8192*512 / 8
        const float4* p = (const float4*)feat + (size_t)j * 2;
        float4 u = p[0], v = p[1];
        *(bf16x8_t*)(fb + (size_t)j * 8) = cvt8(u, v);
    } else if (j < 524288 + 131072) {     // W1 [512][256] -> W1T [256][512]
        int t = j - 524288;
        int k = t >> 8, n = t & 255;
        w1t[n * 512 + k] = (__bf16)W1[t];
    } else if (j < 524288 + 131072 + 32768) { // W2 [256][128] -> W2T [128][256]
        int t = j - 655360;
        int k = t >> 7, n = t & 127;
        w2t[n * 256 + k] = (__bf16)W2[t];
    }
}

// ---- small bf16 GEMM, C (bf16) = X * Y^T ----
template<int MT, int WC>
__global__ __launch_bounds__(256, 2) void gemm_bt_cbf16(
    const __bf16* __restrict__ X, const __bf16* __restrict__ Yb,
    __bf16* __restrict__ C, int K, int N)
{
    constexpr int WR = 4 / WC;
    constexpr int BM = WR * MT * 16;
    constexpr int BN = WC * 64;
    const int mblk = blockIdx.x, nblk = blockIdx.y;
    const int w = threadIdx.x >> 6, lane = threadIdx.x & 63;
    const int wr = w / WC, wc = w % WC;
    const int q = lane >> 4, l16 = lane & 15;
    const int mbase = mblk * BM + wr * (MT * 16);
    const int nbase = nblk * BN + wc * 64;

    f32x4_t acc[MT][4];
    const f32x4_t z = {0.f, 0.f, 0.f, 0.f};
#pragma unroll
    for (int i = 0; i < MT; i++)
#pragma unroll
        for (int jj = 0; jj < 4; jj++) acc[i][jj] = z;

    const __bf16* Xr[MT];
    const __bf16* Yr[4];
#pragma unroll
    for (int i = 0; i < MT; i++) Xr[i] = X + (size_t)(mbase + i * 16 + l16) * K + q * 8;
#pragma unroll
    for (int jj = 0; jj < 4; jj++) Yr[jj] = Yb + (size_t)(nbase + jj * 16 + l16) * K + q * 8;

    for (int k = 0; k < K; k += 32) {
        bf16x8_t a[MT], b[4];
#pragma unroll
        for (int i = 0; i < MT; i++) a[i] = *(const bf16x8_t*)(Xr[i] + k);
#pragma unroll
        for (int jj = 0; jj < 4; jj++) b[jj] = *(const bf16x8_t*)(Yr[jj] + k);
#pragma unroll
        for (int i = 0; i < MT; i++)
#pragma unroll
            for (int jj = 0; jj < 4; jj++) acc[i][jj] = MFMA_BF16(a[i], b[jj], acc[i][jj]);
    }

#pragma unroll
    for (int i = 0; i < MT; i++)
#pragma unroll
        for (int jj = 0; jj < 4; jj++) {
            const int row0 = mbase + i * 16 + q * 4;
            const int col = nbase + jj * 16 + l16;
#pragma unroll
            for (int r = 0; r < 4; r++)
                C[(size_t)(row0 + r) * N + col] = (__bf16)acc[i][jj][r];
        }
}

// ---- adj GEMM, m97-style: fp32 A staged via global_load_lds into
// double-buffered LDS (64x64 tile, 16 KB), source-column XOR swizzle @16B.
// Y bf16 [NN][8192] direct from global (L2-resident). Split-K partials fp32.
// Wave layout 2x2: wave = 32 rows (MT=2) x NN/2 cols (NT=NN/32 n-tiles). ----
template<int NN>
__global__ __launch_bounds__(256, 2) void gemm_adj_lds(
    const float* __restrict__ A, const __bf16* __restrict__ Y,
    float* __restrict__ P, int kchunk)
{
    constexpr int NT = NN / 32;          // n-tiles per wave
    __shared__ float As[2][4096];        // 2 x 64 rows x 64 cols fp32

    const int mblk = blockIdx.x;
    const int ks = blockIdx.y;
    const int w = threadIdx.x >> 6, lane = threadIdx.x & 63;
    const int wr = w >> 1, wc = w & 1;
    const int q = lane >> 4, l16 = lane & 15;
    const int kbase = ks * kchunk;
    const int ntiles = kchunk >> 6;

    // --- staging addresses: wave-instr (w, j) covers tile rows j*16+w*4 .. +4.
    // LDS dst = linear base + lane*16 (DMA constraint). Global source column is
    // XOR-swizzled: granule g16 at row r holds A[.., kk + ((g16 ^ (r&15))*4)].
    const int lrow = lane >> 4;          // 0..3 within wave-instr
    const int lg = lane & 15;            // destination 16B granule in row
    const float* gsrc[4];
    int loff[4];
#pragma unroll
    for (int j = 0; j < 4; j++) {
        const int row = j * 16 + w * 4 + lrow;            // tile-local row
        const int colswz = ((lg ^ (row & 15)) << 2);      // swizzled source col
        gsrc[j] = A + (size_t)(mblk * 64 + row) * 8192 + kbase + colswz;
        loff[j] = row * 64 + (lg << 2);                   // contiguous LDS dst
    }

    const __bf16* Yr[NT];
#pragma unroll
    for (int jj = 0; jj < NT; jj++)
        Yr[jj] = Y + (size_t)(wc * (NN / 2) + jj * 16 + l16) * 8192 + q * 8;

    f32x4_t acc[2][NT];
    const f32x4_t z = {0.f, 0.f, 0.f, 0.f};
#pragma unroll
    for (int i = 0; i < 2; i++)
#pragma unroll
        for (int jj = 0; jj < NT; jj++) acc[i][jj] = z;

    // preload tile 0
#pragma unroll
    for (int j = 0; j < 4; j++) gload_lds16(gsrc[j], &As[0][0] + loff[j]);

    int buf = 0;
    for (int kt = 0; kt < ntiles; kt++) {
        __syncthreads();   // drains vmcnt(0): tile kt DMA complete, prev compute done
        if (kt + 1 < ntiles) {
            const int koff = (kt + 1) << 6;
#pragma unroll
            for (int j = 0; j < 4; j++)
                gload_lds16(gsrc[j] + koff, &As[buf ^ 1][0] + loff[j]);
        }
        const int kk = kbase + (kt << 6);
        const float* __restrict__ L = &As[buf][0];
#pragma unroll
        for (int s = 0; s < 2; s++) {
            bf16x8_t b[NT];
#pragma unroll
            for (int jj = 0; jj < NT; jj++)
                b[jj] = *(const bf16x8_t*)(Yr[jj] + kk + s * 32);
            bf16x8_t a[2];
#pragma unroll
            for (int i = 0; i < 2; i++) {
                const int r = wr * 32 + i * 16 + l16;
                const int g0 = ((s * 8 + q * 2) ^ (r & 15)) << 2;
                const int g1 = ((s * 8 + q * 2 + 1) ^ (r & 15)) << 2;
                float4 u = *(const float4*)(L + r * 64 + g0);
                float4 v = *(const float4*)(L + r * 64 + g1);
                a[i] = cvt8(u, v);
            }
#pragma unroll
            for (int i = 0; i < 2; i++)
#pragma unroll
                for (int jj = 0; jj < NT; jj++)
                    acc[i][jj] = MFMA_BF16(a[i], b[jj], acc[i][jj]);
        }
        buf ^= 1;
    }

#pragma unroll
    for (int i = 0; i < 2; i++)
#pragma unroll
        for (int jj = 0; jj < NT; jj++) {
            const int row0 = mblk * 64 + wr * 32 + i * 16 + q * 4;
            const int col = wc * (NN / 2) + jj * 16 + l16;
            float* pp = P + ((size_t)ks * 8192 + row0) * NN + col;
#pragma unroll
            for (int r = 0; r < 4; r++) pp[(size_t)r * NN] = acc[i][jj][r];
        }
}

// ---- epilogue 1: h1 = relu(sum_ks partial + b1) -> bf16 [8192][256] ----
__global__ __launch_bounds__(256) void epi_relu_bias(
    const float* __restrict__ P, const float* __restrict__ bias,
    __bf16* __restrict__ H)
{
    const size_t SL = (size_t)8192 * 256;
    const size_t idx = ((size_t)blockIdx.x * 256 + threadIdx.x) * 4;
    float4 s0 = *(const float4*)(P + idx);
    float4 s1 = *(const float4*)(P + SL + idx);
    float4 s2 = *(const float4*)(P + 2 * SL + idx);
    float4 s3 = *(const float4*)(P + 3 * SL + idx);
    const int col = (int)(idx & 255);
    float4 bb = *(const float4*)(bias + col);
    float r0 = fmaxf(s0.x + s1.x + s2.x + s3.x + bb.x, 0.f);
    float r1 = fmaxf(s0.y + s1.y + s2.y + s3.y + bb.y, 0.f);
    float r2 = fmaxf(s0.z + s1.z + s2.z + s3.z + bb.z, 0.f);
    float r3 = fmaxf(s0.w + s1.w + s2.w + s3.w + bb.w, 0.f);
    bf16x4_t o;
    o[0] = (__bf16)r0; o[1] = (__bf16)r1; o[2] = (__bf16)r2; o[3] = (__bf16)r3;
    *(bf16x4_t*)(H + idx) = o;
}

// ---- epilogue 2: h = sum_ks partial + b2 -> fp32 d_out tail AND bf16 copy ----
__global__ __launch_bounds__(256) void epi_bias_out(
    const float* __restrict__ P, const float* __restrict__ bias,
    float* __restrict__ Hout, __bf16* __restrict__ Hbf)
{
    const size_t SL = (size_t)8192 * 128;
    const size_t idx = ((size_t)blockIdx.x * 256 + threadIdx.x) * 4;
    float4 s0 = *(const float4*)(P + idx);
    float4 s1 = *(const float4*)(P + SL + idx);
    float4 s2 = *(const float4*)(P + 2 * SL + idx);
    float4 s3 = *(const float4*)(P + 3 * SL + idx);
    const int col = (int)(idx & 127);
    float4 bb = *(const float4*)(bias + col);
    float4 o;
    o.x = s0.x + s1.x + s2.x + s3.x + bb.x;
    o.y = s0.y + s1.y + s2.y + s3.y + bb.y;
    o.z = s0.z + s1.z + s2.z + s3.z + bb.z;
    o.w = s0.w + s1.w + s2.w + s3.w + bb.w;
    *(float4*)(Hout + idx) = o;
    bf16x4_t ob;
    ob[0] = (__bf16)o.x; ob[1] = (__bf16)o.y; ob[2] = (__bf16)o.z; ob[3] = (__bf16)o.w;
    *(bf16x4_t*)(Hbf + idx) = ob;
}

// ---- decoder: out[r][s] = sigmoid(h[r,:].h[s,:]), K=128 unrolled ----
__global__ __launch_bounds__(256, 2) void gemm_sig(
    const __bf16* __restrict__ H, float* __restrict__ out)
{
    const int mblk = blockIdx.x, nblk = blockIdx.y;
    const int w = threadIdx.x >> 6, lane = threadIdx.x & 63;
    const int wr = w >> 1, wc = w & 1;
    const int q = lane >> 4, l16 = lane & 15;
    const int mbase = mblk * 128 + wr * 64;
    const int nbase = nblk * 128 + wc * 64;

    f32x4_t acc[4][4];
    const f32x4_t z = {0.f, 0.f, 0.f, 0.f};
#pragma unroll
    for (int i = 0; i < 4; i++)
#pragma unroll
        for (int jj = 0; jj < 4; jj++) acc[i][jj] = z;

#pragma unroll
    for (int k = 0; k < 128; k += 32) {
        bf16x8_t a[4], b[4];
#pragma unroll
        for (int i = 0; i < 4; i++)
            a[i] = *(const bf16x8_t*)(H + (size_t)(mbase + i * 16 + l16) * 128 + k + q * 8);
#pragma unroll
        for (int jj = 0; jj < 4; jj++)
            b[jj] = *(const bf16x8_t*)(H + (size_t)(nbase + jj * 16 + l16) * 128 + k + q * 8);
#pragma unroll
        for (int i = 0; i < 4; i++)
#pragma unroll
            for (int jj = 0; jj < 4; jj++) acc[i][jj] = MFMA_BF16(a[i], b[jj], acc[i][jj]);
    }

#pragma unroll
    for (int i = 0; i < 4; i++)
#pragma unroll
        for (int jj = 0; jj < 4; jj++) {
            const int row0 = mbase + i * 16 + q * 4;
            const int col = nbase + jj * 16 + l16;
#pragma unroll
            for (int r = 0; r < 4; r++) {
                float x = acc[i][jj][r];
                out[(size_t)(row0 + r) * 8192 + col] = 1.0f / (1.0f + __expf(-x));
            }
        }
}

extern "C" void kernel_launch(void* const* d_in, const int* in_sizes, int n_in,
                              void* d_out, int out_size, void* d_ws, size_t ws_size,
                              hipStream_t stream)
{
    const float* adj  = (const float*)d_in[0];
    const float* feat = (const float*)d_in[1];
    const float* W1   = (const float*)d_in[2];
    const float* b1   = (const float*)d_in[3];
    const float* W2   = (const float*)d_in[4];
    const float* b2   = (const float*)d_in[5];
    float* out = (float*)d_out;

    // workspace layout (~52.3 MB total)
    char* p = (char*)d_ws;
    __bf16* featbf = (__bf16*)p; p += (size_t)8192 * 512 * 2;  // 8 MB
    __bf16* W1T    = (__bf16*)p; p += (size_t)256 * 512 * 2;   // 256 KB
    __bf16* W2T    = (__bf16*)p; p += (size_t)128 * 256 * 2;   // 64 KB
    __bf16* t1T    = (__bf16*)p; p += (size_t)256 * 8192 * 2;  // 4 MB
    __bf16* h1     = (__bf16*)p; p += (size_t)8192 * 256 * 2;  // 4 MB
    __bf16* t2T    = (__bf16*)p; p += (size_t)128 * 8192 * 2;  // 2 MB
    __bf16* hbf    = (__bf16*)p; p += (size_t)8192 * 128 * 2;  // 2 MB
    float* part    = (float*)p;                                 // 32 MB (reused 16 MB)

    // 1. casts
    cast_all<<<2688, 256, 0, stream>>>(feat, W1, W2, featbf, W1T, W2T);
    // 2. t1T[256][8192] = W1T * feat^T
    gemm_bt_cbf16<2, 2><<<dim3(4, 64), 256, 0, stream>>>(W1T, featbf, t1T, 512, 8192);
    // 3. partials of adj @ t1  (split-K=4, LDS-staged)
    gemm_adj_lds<256><<<dim3(128, 4), 256, 0, stream>>>(adj, t1T, part, 2048);
    // 4. h1 = relu(sum + b1) -> bf16
    epi_relu_bias<<<2048, 256, 0, stream>>>(part, b1, h1);
    // 5. t2T[128][8192] = W2T * h1^T
    gemm_bt_cbf16<2, 2><<<dim3(2, 64), 256, 0, stream>>>(W2T, h1, t2T, 256, 8192);
    // 6. partials of adj @ t2  (split-K=4, LDS-staged)
    gemm_adj_lds<128><<<dim3(128, 4), 256, 0, stream>>>(adj, t2T, part, 2048);
    // 7. h = sum + b2 -> fp32 out tail + bf16 copy
    epi_bias_out<<<1024, 256, 0, stream>>>(part, b2, out + (size_t)8192 * 8192, hbf);
    // 8. out = sigmoid(h @ h^T)
    gemm_sig<<<dim3(64, 64), 256, 0, stream>>>(hbf, out);
}

// Round 3
// 624.962 us; speedup vs baseline: 1.2795x; 1.1509x over previous
//
#include <hip/hip_runtime.h>

// GAE forward on MI355X.
// Pipeline: cast -> t1T=W1T@featT -> h1=relu(adj@t1+b1) [split-K] ->
//           t2T=W2T@h1T -> h=adj@t2+b2 [split-K] -> out=sigmoid(h@hT), h.
// All MFMA GEMMs use the "bt" convention: X[M,K], Y[N,K] row-major, C = X*Y^T.
// Frag layout (m89-verified): A/B lane = X[l16][k+q*8..+8] (16B load);
// C/D: col = lane&15, row = q*4 + reg.
//
// R3: adj-GEMM wave-grid 1x4 (wave = all 64 rows x NN/4 cols) -> B-operand
// global traffic halved (no wc duplication; 32 KB/block-iter == unique tile
// bytes). adj DMA carries NT cpol (aux=2) so streaming adj stops evicting the
// B panel from L2. b-loads issued BEFORE the barrier/DMA so in-order vmcnt
// never forces a mid-iteration drain of the prefetch.

typedef __bf16 bf16x8_t __attribute__((ext_vector_type(8)));
typedef __bf16 bf16x4_t __attribute__((ext_vector_type(4)));
typedef float  f32x4_t  __attribute__((ext_vector_type(4)));

#define MFMA_BF16(a, b, c) __builtin_amdgcn_mfma_f32_16x16x32_bf16((a), (b), (c), 0, 0, 0)

__device__ __forceinline__ bf16x8_t cvt8(float4 u, float4 v) {
    bf16x8_t o;
    o[0] = (__bf16)u.x; o[1] = (__bf16)u.y; o[2] = (__bf16)u.z; o[3] = (__bf16)u.w;
    o[4] = (__bf16)v.x; o[5] = (__bf16)v.y; o[6] = (__bf16)v.z; o[7] = (__bf16)v.w;
    return o;
}

// width-16 global->LDS DMA; NT=1 sets the non-temporal cache policy (CPol bit1)
template<int AUX>
__device__ __forceinline__ void gload_lds16(const float* g, float* l) {
    __builtin_amdgcn_global_load_lds(
        (const __attribute__((address_space(1))) unsigned int*)g,
        (__attribute__((address_space(3))) unsigned int*)l, 16, 0, AUX);
}

// ---- cast feature -> bf16 (8 elems/thread), W1 -> W1T bf16, W2 -> W2T bf16 ----
__global__ __launch_bounds__(256) void cast_all(
    const float* __restrict__ feat, const float* __restrict__ W1,
    const float* __restrict__ W2, __bf16* __restrict__ fb,
    __bf16* __restrict__ w1t, __bf16* __restrict__ w2t)
{
    const int j = blockIdx.x * 256 + threadIdx.x;
    if (j < 524288) {                     // feature: 8192*512 / 8
        const float4* p = (const float4*)feat + (size_t)j * 2;
        float4 u = p[0], v = p[1];
        *(bf16x8_t*)(fb + (size_t)j * 8) = cvt8(u, v);
    } else if (j < 524288 + 131072) {     // W1 [512][256] -> W1T [256][512]
        int t = j - 524288;
        int k = t >> 8, n = t & 255;
        w1t[n * 512 + k] = (__bf16)W1[t];
    } else if (j < 524288 + 131072 + 32768) { // W2 [256][128] -> W2T [128][256]
        int t = j - 655360;
        int k = t >> 7, n = t & 127;
        w2t[n * 256 + k] = (__bf16)W2[t];
    }
}

// ---- small bf16 GEMM, C (bf16) = X * Y^T ----
template<int MT, int WC>
__global__ __launch_bounds__(256, 2) void gemm_bt_cbf16(
    const __bf16* __restrict__ X, const __bf16* __restrict__ Yb,
    __bf16* __restrict__ C, int K, int N)
{
    constexpr int WR = 4 / WC;
    constexpr int BM = WR * MT * 16;
    constexpr int BN = WC * 64;
    const int mblk = blockIdx.x, nblk = blockIdx.y;
    const int w = threadIdx.x >> 6, lane = threadIdx.x & 63;
    const int wr = w / WC, wc = w % WC;
    const int q = lane >> 4, l16 = lane & 15;
    const int mbase = mblk * BM + wr * (MT * 16);
    const int nbase = nblk * BN + wc * 64;

    f32x4_t acc[MT][4];
    const f32x4_t z = {0.f, 0.f, 0.f, 0.f};
#pragma unroll
    for (int i = 0; i < MT; i++)
#pragma unroll
        for (int jj = 0; jj < 4; jj++) acc[i][jj] = z;

    const __bf16* Xr[MT];
    const __bf16* Yr[4];
#pragma unroll
    for (int i = 0; i < MT; i++) Xr[i] = X + (size_t)(mbase + i * 16 + l16) * K + q * 8;
#pragma unroll
    for (int jj = 0; jj < 4; jj++) Yr[jj] = Yb + (size_t)(nbase + jj * 16 + l16) * K + q * 8;

    for (int k = 0; k < K; k += 32) {
        bf16x8_t a[MT], b[4];
#pragma unroll
        for (int i = 0; i < MT; i++) a[i] = *(const bf16x8_t*)(Xr[i] + k);
#pragma unroll
        for (int jj = 0; jj < 4; jj++) b[jj] = *(const bf16x8_t*)(Yr[jj] + k);
#pragma unroll
        for (int i = 0; i < MT; i++)
#pragma unroll
            for (int jj = 0; jj < 4; jj++) acc[i][jj] = MFMA_BF16(a[i], b[jj], acc[i][jj]);
    }

#pragma unroll
    for (int i = 0; i < MT; i++)
#pragma unroll
        for (int jj = 0; jj < 4; jj++) {
            const int row0 = mbase + i * 16 + q * 4;
            const int col = nbase + jj * 16 + l16;
#pragma unroll
            for (int r = 0; r < 4; r++)
                C[(size_t)(row0 + r) * N + col] = (__bf16)acc[i][jj][r];
        }
}

// ---- adj GEMM: fp32 A staged via NT global_load_lds into double-buffered LDS
// (64x64 tile, 16 KB), source-column XOR swizzle @16B. Wave-grid 1x4: each
// wave computes all 64 rows (MT=4) x NN/4 cols (NT=NN/64 tiles). B (Y) loaded
// per-wave from global — duplication-free at this blocking, L2-resident since
// adj is NT. b-loads issued before the barrier so vmcnt stays fine-grained. ----
template<int NN>
__global__ __launch_bounds__(256, 2) void gemm_adj_lds(
    const float* __restrict__ A, const __bf16* __restrict__ Y,
    float* __restrict__ P, int kchunk)
{
    constexpr int NT = NN / 64;          // n-tiles per wave (1x4 wave grid)
    __shared__ float As[2][4096];        // 2 x 64 rows x 64 cols fp32

    const int mblk = blockIdx.x;
    const int ks = blockIdx.y;
    const int w = threadIdx.x >> 6, lane = threadIdx.x & 63;
    const int q = lane >> 4, l16 = lane & 15;
    const int kbase = ks * kchunk;
    const int ntiles = kchunk >> 6;

    // staging: wave-instr (w, j) covers tile rows j*16+w*4 .. +4.
    // LDS dst = uniform base + lane*16 (DMA constraint); global source column
    // XOR-swizzled: granule g at row r holds A[.., kk + ((g ^ (r&15))*4)].
    const int lrow = lane >> 4;
    const int lg = lane & 15;
    const float* gsrc[4];
    int loff[4];
#pragma unroll
    for (int j = 0; j < 4; j++) {
        const int row = j * 16 + w * 4 + lrow;
        const int colswz = ((lg ^ (row & 15)) << 2);
        gsrc[j] = A + (size_t)(mblk * 64 + row) * 8192 + kbase + colswz;
        loff[j] = row * 64 + (lg << 2);
    }

    const __bf16* Yr[NT];
#pragma unroll
    for (int jj = 0; jj < NT; jj++)
        Yr[jj] = Y + (size_t)(w * (NN / 4) + jj * 16 + l16) * 8192 + q * 8;

    f32x4_t acc[4][NT];
    const f32x4_t z = {0.f, 0.f, 0.f, 0.f};
#pragma unroll
    for (int i = 0; i < 4; i++)
#pragma unroll
        for (int jj = 0; jj < NT; jj++) acc[i][jj] = z;

    // preload tile 0 (NT cpol: don't pollute L2 with streaming adj)
#pragma unroll
    for (int j = 0; j < 4; j++) gload_lds16<2>(gsrc[j], &As[0][0] + loff[j]);

    int buf = 0;
    for (int kt = 0; kt < ntiles; kt++) {
        const int kk = kbase + (kt << 6);

        // B fragments for this K-tile, issued BEFORE the barrier: they are
        // L2-hits and complete during the barrier's DMA drain.
        bf16x8_t breg[2][NT];
#pragma unroll
        for (int s = 0; s < 2; s++)
#pragma unroll
            for (int jj = 0; jj < NT; jj++)
                breg[s][jj] = *(const bf16x8_t*)(Yr[jj] + kk + s * 32);

        __syncthreads();   // tile kt DMA complete; prev compute done

        if (kt + 1 < ntiles) {
            const int koff = (kt + 1) << 6;
#pragma unroll
            for (int j = 0; j < 4; j++)
                gload_lds16<2>(gsrc[j] + koff, &As[buf ^ 1][0] + loff[j]);
        }

        const float* __restrict__ L = &As[buf][0];
#pragma unroll
        for (int s = 0; s < 2; s++) {
            bf16x8_t a[4];
#pragma unroll
            for (int i = 0; i < 4; i++) {
                const int r = i * 16 + l16;              // tile-local row
                const int g0 = ((s * 8 + q * 2) ^ l16) << 2;
                const int g1 = ((s * 8 + q * 2 + 1) ^ l16) << 2;
                float4 u = *(const float4*)(L + r * 64 + g0);
                float4 v = *(const float4*)(L + r * 64 + g1);
                a[i] = cvt8(u, v);
            }
#pragma unroll
            for (int i = 0; i < 4; i++)
#pragma unroll
                for (int jj = 0; jj < NT; jj++)
                    acc[i][jj] = MFMA_BF16(a[i], breg[s][jj], acc[i][jj]);
        }
        buf ^= 1;
    }

#pragma unroll
    for (int i = 0; i < 4; i++)
#pragma unroll
        for (int jj = 0; jj < NT; jj++) {
            const int row0 = mblk * 64 + i * 16 + q * 4;
            const int col = w * (NN / 4) + jj * 16 + l16;
            float* pp = P + ((size_t)ks * 8192 + row0) * NN + col;
#pragma unroll
            for (int r = 0; r < 4; r++) pp[(size_t)r * NN] = acc[i][jj][r];
        }
}

// ---- epilogue 1: h1 = relu(sum_ks partial + b1) -> bf16 [8192][256] ----
__global__ __launch_bounds__(256) void epi_relu_bias(
    const float* __restrict__ P, const float* __restrict__ bias,
    __bf16* __restrict__ H)
{
    const size_t SL = (size_t)8192 * 256;
    const size_t idx = ((size_t)blockIdx.x * 256 + threadIdx.x) * 4;
    float4 s0 = *(const float4*)(P + idx);
    float4 s1 = *(const float4*)(P + SL + idx);
    float4 s2 = *(const float4*)(P + 2 * SL + idx);
    float4 s3 = *(const float4*)(P + 3 * SL + idx);
    const int col = (int)(idx & 255);
    float4 bb = *(const float4*)(bias + col);
    float r0 = fmaxf(s0.x + s1.x + s2.x + s3.x + bb.x, 0.f);
    float r1 = fmaxf(s0.y + s1.y + s2.y + s3.y + bb.y, 0.f);
    float r2 = fmaxf(s0.z + s1.z + s2.z + s3.z + bb.z, 0.f);
    float r3 = fmaxf(s0.w + s1.w + s2.w + s3.w + bb.w, 0.f);
    bf16x4_t o;
    o[0] = (__bf16)r0; o[1] = (__bf16)r1; o[2] = (__bf16)r2; o[3] = (__bf16)r3;
    *(bf16x4_t*)(H + idx) = o;
}

// ---- epilogue 2: h = sum_ks partial + b2 -> fp32 d_out tail AND bf16 copy ----
__global__ __launch_bounds__(256) void epi_bias_out(
    const float* __restrict__ P, const float* __restrict__ bias,
    float* __restrict__ Hout, __bf16* __restrict__ Hbf)
{
    const size_t SL = (size_t)8192 * 128;
    const size_t idx = ((size_t)blockIdx.x * 256 + threadIdx.x) * 4;
    float4 s0 = *(const float4*)(P + idx);
    float4 s1 = *(const float4*)(P + SL + idx);
    float4 s2 = *(const float4*)(P + 2 * SL + idx);
    float4 s3 = *(const float4*)(P + 3 * SL + idx);
    const int col = (int)(idx & 127);
    float4 bb = *(const float4*)(bias + col);
    float4 o;
    o.x = s0.x + s1.x + s2.x + s3.x + bb.x;
    o.y = s0.y + s1.y + s2.y + s3.y + bb.y;
    o.z = s0.z + s1.z + s2.z + s3.z + bb.z;
    o.w = s0.w + s1.w + s2.w + s3.w + bb.w;
    *(float4*)(Hout + idx) = o;
    bf16x4_t ob;
    ob[0] = (__bf16)o.x; ob[1] = (__bf16)o.y; ob[2] = (__bf16)o.z; ob[3] = (__bf16)o.w;
    *(bf16x4_t*)(Hbf + idx) = ob;
}

// ---- decoder: out[r][s] = sigmoid(h[r,:].h[s,:]), K=128 unrolled ----
__global__ __launch_bounds__(256, 2) void gemm_sig(
    const __bf16* __restrict__ H, float* __restrict__ out)
{
    const int mblk = blockIdx.x, nblk = blockIdx.y;
    const int w = threadIdx.x >> 6, lane = threadIdx.x & 63;
    const int wr = w >> 1, wc = w & 1;
    const int q = lane >> 4, l16 = lane & 15;
    const int mbase = mblk * 128 + wr * 64;
    const int nbase = nblk * 128 + wc * 64;

    f32x4_t acc[4][4];
    const f32x4_t z = {0.f, 0.f, 0.f, 0.f};
#pragma unroll
    for (int i = 0; i < 4; i++)
#pragma unroll
        for (int jj = 0; jj < 4; jj++) acc[i][jj] = z;

#pragma unroll
    for (int k = 0; k < 128; k += 32) {
        bf16x8_t a[4], b[4];
#pragma unroll
        for (int i = 0; i < 4; i++)
            a[i] = *(const bf16x8_t*)(H + (size_t)(mbase + i * 16 + l16) * 128 + k + q * 8);
#pragma unroll
        for (int jj = 0; jj < 4; jj++)
            b[jj] = *(const bf16x8_t*)(H + (size_t)(nbase + jj * 16 + l16) * 128 + k + q * 8);
#pragma unroll
        for (int i = 0; i < 4; i++)
#pragma unroll
            for (int jj = 0; jj < 4; jj++) acc[i][jj] = MFMA_BF16(a[i], b[jj], acc[i][jj]);
    }

#pragma unroll
    for (int i = 0; i < 4; i++)
#pragma unroll
        for (int jj = 0; jj < 4; jj++) {
            const int row0 = mbase + i * 16 + q * 4;
            const int col = nbase + jj * 16 + l16;
#pragma unroll
            for (int r = 0; r < 4; r++) {
                float x = acc[i][jj][r];
                out[(size_t)(row0 + r) * 8192 + col] = 1.0f / (1.0f + __expf(-x));
            }
        }
}

extern "C" void kernel_launch(void* const* d_in, const int* in_sizes, int n_in,
                              void* d_out, int out_size, void* d_ws, size_t ws_size,
                              hipStream_t stream)
{
    const float* adj  = (const float*)d_in[0];
    const float* feat = (const float*)d_in[1];
    const float* W1   = (const float*)d_in[2];
    const float* b1   = (const float*)d_in[3];
    const float* W2   = (const float*)d_in[4];
    const float* b2   = (const float*)d_in[5];
    float* out = (float*)d_out;

    // workspace layout (~52.3 MB total)
    char* p = (char*)d_ws;
    __bf16* featbf = (__bf16*)p; p += (size_t)8192 * 512 * 2;  // 8 MB
    __bf16* W1T    = (__bf16*)p; p += (size_t)256 * 512 * 2;   // 256 KB
    __bf16* W2T    = (__bf16*)p; p += (size_t)128 * 256 * 2;   // 64 KB
    __bf16* t1T    = (__bf16*)p; p += (size_t)256 * 8192 * 2;  // 4 MB
    __bf16* h1     = (__bf16*)p; p += (size_t)8192 * 256 * 2;  // 4 MB
    __bf16* t2T    = (__bf16*)p; p += (size_t)128 * 8192 * 2;  // 2 MB
    __bf16* hbf    = (__bf16*)p; p += (size_t)8192 * 128 * 2;  // 2 MB
    float* part    = (float*)p;                                 // 32 MB (reused 16 MB)

    // 1. casts
    cast_all<<<2688, 256, 0, stream>>>(feat, W1, W2, featbf, W1T, W2T);
    // 2. t1T[256][8192] = W1T * feat^T
    gemm_bt_cbf16<2, 2><<<dim3(4, 64), 256, 0, stream>>>(W1T, featbf, t1T, 512, 8192);
    // 3. partials of adj @ t1  (split-K=4, LDS-staged, NT adj)
    gemm_adj_lds<256><<<dim3(128, 4), 256, 0, stream>>>(adj, t1T, part, 2048);
    // 4. h1 = relu(sum + b1) -> bf16
    epi_relu_bias<<<2048, 256, 0, stream>>>(part, b1, h1);
    // 5. t2T[128][8192] = W2T * h1^T
    gemm_bt_cbf16<2, 2><<<dim3(2, 64), 256, 0, stream>>>(W2T, h1, t2T, 256, 8192);
    // 6. partials of adj @ t2  (split-K=4, LDS-staged, NT adj)
    gemm_adj_lds<128><<<dim3(128, 4), 256, 0, stream>>>(adj, t2T, part, 2048);
    // 7. h = sum + b2 -> fp32 out tail + bf16 copy
    epi_bias_out<<<1024, 256, 0, stream>>>(part, b2, out + (size_t)8192 * 8192, hbf);
    // 8. out = sigmoid(h @ h^T)
    gemm_sig<<<dim3(64, 64), 256, 0, stream>>>(hbf, out);
}